// Round 19
// baseline (146.749 us; speedup 1.0000x reference)
//
#include <hip/hip_runtime.h>
#include <hip/hip_bf16.h>

#define D 64
#define RPB 1024         // rows per bin bucket (rl fits in 10 bits; col 17 bits -> 27)
#define RSH 10           // log2(RPB)
#define NBB 128          // max buckets (n_nodes <= 131072)
#define CPAD 16          // ints per padded counter (64 B line)
#define NSB 1024         // scatter-role blocks in the fused kernel
#define NGB 1024         // gemm-role blocks (total 2048 = 8 blocks/CU, all resident)

// ===========================================================================
// Fused bin_scatter + gemm: blocks [0,NSB) partition edges into coarse
// buckets (latency-bound); blocks [NSB,NSB+NGB) compute support=x@(W0+W1+W2)
// (BW-bound). Data-independent; fusing overlaps them on the CUs. 2048 blocks
// = 8/CU so every scatter block is resident from t=0.
// ===========================================================================
__global__ __launch_bounds__(256) void fused_scatter_gemm_kernel(
        const int* __restrict__ rows, const int* __restrict__ cols,
        const float* __restrict__ vals, int ne,
        int* __restrict__ cursor, int nb, int2* __restrict__ binned,
        const float* __restrict__ x, const float* __restrict__ w0,
        const float* __restrict__ w1, const float* __restrict__ w2,
        __hip_bfloat16* __restrict__ support, int n) {
    __shared__ float Ws[D * D];
    __shared__ float xs[4][D];
    __shared__ int lcnt[NBB];
    __shared__ int lbase[NBB];
    const int tid = threadIdx.x;

    if (blockIdx.x < NSB) {
        // ---- bin_scatter body (R15-proven) ----
        const int ce = (ne + NSB - 1) / NSB;
        const int e0 = blockIdx.x * ce;
        const int e1 = min(ne, e0 + ce);

        for (int i = tid; i < nb; i += 256) lcnt[i] = 0;
        __syncthreads();
        for (int e = e0 + tid; e < e1; e += 256) atomicAdd(&lcnt[rows[e] >> RSH], 1);
        __syncthreads();
        for (int b = tid; b < nb; b += 256) {
            int c = lcnt[b];
            lbase[b] = c ? atomicAdd(&cursor[b * CPAD], c) : 0;
        }
        __syncthreads();
        for (int i = tid; i < nb; i += 256) lcnt[i] = 0;   // reuse as local cursor
        __syncthreads();
        for (int e = e0 + tid; e < e1; e += 256) {
            int r = rows[e];
            int b = r >> RSH;
            int loc = atomicAdd(&lcnt[b], 1);
            int2 cv;
            cv.x = ((r & (RPB - 1)) << 17) | cols[e];
            cv.y = __float_as_int(vals[e]);
            binned[lbase[b] + loc] = cv;
        }
    } else {
        // ---- gemm body (R15-proven) ----
        for (int i = tid; i < D * D; i += 256)
            Ws[i] = w0[i] + w1[i] + w2[i];
        __syncthreads();
        const int wid  = tid >> 6;
        const int lane = tid & 63;
        const int gb = blockIdx.x - NSB;
        int row = gb * 4 + wid;
        const int nw = NGB * 4;
        for (; row < n; row += nw) {
            xs[wid][lane] = x[(size_t)row * D + lane];
            float acc = 0.0f;
#pragma unroll
            for (int k = 0; k < D; ++k) acc += xs[wid][k] * Ws[k * D + lane];
            support[(size_t)row * D + lane] = __float2bfloat16(acc);
        }
    }
}

// f32-support gemm for the fallback path
__global__ __launch_bounds__(256) void gemm_f32_kernel(const float* __restrict__ x,
                                                       const float* __restrict__ w0,
                                                       const float* __restrict__ w1,
                                                       const float* __restrict__ w2,
                                                       float* __restrict__ support,
                                                       int n) {
    __shared__ float Ws[D * D];
    __shared__ float xs[4][D];
    for (int i = threadIdx.x; i < D * D; i += 256)
        Ws[i] = w0[i] + w1[i] + w2[i];
    __syncthreads();
    const int wid  = threadIdx.x >> 6;
    const int lane = threadIdx.x & 63;
    int row = blockIdx.x * 4 + wid;
    const int nw = gridDim.x * 4;
    for (; row < n; row += nw) {
        xs[wid][lane] = x[(size_t)row * D + lane];
        float acc = 0.0f;
#pragma unroll
        for (int k = 0; k < D; ++k) acc += xs[wid][k] * Ws[k * D + lane];
        support[(size_t)row * D + lane] = acc;
    }
}

// ===========================================================================
// zero -> hist (98 coarse buckets) -> scan (R15-proven)
// ===========================================================================
__global__ __launch_bounds__(256) void zero_kernel(int* __restrict__ p, int n) {
    int i = blockIdx.x * 256 + threadIdx.x;
    int stride = gridDim.x * 256;
    for (; i < n; i += stride) p[i] = 0;
}

__global__ __launch_bounds__(256) void bucket_hist_kernel(const int* __restrict__ rows,
                                                          int ne, int* __restrict__ gcnt,
                                                          int nb) {
    __shared__ int lcnt[NBB];
    for (int i = threadIdx.x; i < nb; i += 256) lcnt[i] = 0;
    __syncthreads();
    int i = blockIdx.x * 256 + threadIdx.x;
    int stride = gridDim.x * 256;
    for (; i < ne; i += stride) atomicAdd(&lcnt[rows[i] >> RSH], 1);
    __syncthreads();
    for (int b = threadIdx.x; b < nb; b += 256) {
        int c = lcnt[b];
        if (c) atomicAdd(&gcnt[b * CPAD], c);
    }
}

// 1 block: exclusive scan -> base[nb+1], cursor copy; also rowptr[n] sentinel
__global__ __launch_bounds__(256) void bucket_scan_kernel(const int* __restrict__ gcnt,
                                                          int nb,
                                                          int* __restrict__ base,
                                                          int* __restrict__ cursor,
                                                          int* __restrict__ rowptr,
                                                          int n) {
    __shared__ int ts[256];
    const int tid = threadIdx.x;
    int v = (tid < nb) ? gcnt[tid * CPAD] : 0;
    ts[tid] = v;
    __syncthreads();
    for (int off = 1; off < 256; off <<= 1) {
        int t = (tid >= off) ? ts[tid - off] : 0;
        __syncthreads();
        ts[tid] += t;
        __syncthreads();
    }
    int excl = ts[tid] - v;
    if (tid < nb) { base[tid] = excl; cursor[tid * CPAD] = excl; }
    if (tid == 255) { base[nb] = ts[255]; rowptr[n] = ts[255]; }
}

// ===========================================================================
// local_csr (R14/R15-proven): grid = nb*4 blocks of 512 threads. Block (b,q):
// full 1024-bin hist of bucket b's segment, in-block scan, rowptr for its
// 2 bins/thread, then scatter ONLY quarter q's rows (256) into its
// contiguous window (streaming full-line writes, L2-resident).
// ===========================================================================
__global__ __launch_bounds__(512) void local_csr_kernel(const int* __restrict__ base,
                                                        const int2* __restrict__ binned,
                                                        int* __restrict__ rowptr,
                                                        int2* __restrict__ csr,
                                                        int n) {
    __shared__ int lh[RPB];     // hist -> cursor (4 KB)
    __shared__ int ts[512];
    const int tid = threadIdx.x;
    const int b = blockIdx.x >> 2;
    const int q = blockIdx.x & 3;
    const int jb = base[b], je = base[b + 1];

    lh[2 * tid] = 0; lh[2 * tid + 1] = 0;
    __syncthreads();
    for (int j = jb + tid; j < je; j += 512)
        atomicAdd(&lh[binned[j].x >> 17], 1);
    __syncthreads();

    const int v0 = lh[2 * tid], v1 = lh[2 * tid + 1];
    const int tsum = v0 + v1;
    ts[tid] = tsum;
    __syncthreads();
    for (int off = 1; off < 512; off <<= 1) {
        int t = (tid >= off) ? ts[tid - off] : 0;
        __syncthreads();
        ts[tid] += t;
        __syncthreads();
    }
    int excl = ts[tid] - tsum + jb;
    __syncthreads();           // everyone done reading lh as hist

    const int r0 = b * RPB + 2 * tid;
    lh[2 * tid] = excl;
    if (r0 < n) rowptr[r0] = excl;
    lh[2 * tid + 1] = excl + v0;
    if (r0 + 1 < n) rowptr[r0 + 1] = excl + v0;
    __syncthreads();

    for (int j = jb + tid; j < je; j += 512) {
        int2 e = binned[j];
        int rl = e.x >> 17;
        if ((rl >> 8) == q) {
            int pos = atomicAdd(&lh[rl], 1);
            int2 o; o.x = e.x & 0x1FFFF; o.y = e.y;
            csr[pos] = o;
        }
    }
}

// ===========================================================================
// Pull (R13/R15-proven): 2 rows per wave, uint (2 bf16) gathers, register
// accumulate, 8-deep unroll.
// ===========================================================================
__global__ __launch_bounds__(256) void pull2_kernel(const int* __restrict__ rowptr,
                                                    const int2* __restrict__ csr,
                                                    const unsigned int* __restrict__ sup32,
                                                    const float* __restrict__ bias,
                                                    float* __restrict__ out, int n) {
    const int tid  = threadIdx.x;
    const int lane = tid & 63;
    const int half = lane >> 5;
    const int sub  = lane & 31;
    const int wave = blockIdx.x * 4 + (tid >> 6);
    const int nwave = gridDim.x * 4;
    const float2 b2 = reinterpret_cast<const float2*>(bias)[sub];

    for (int w = wave; 2 * w < n; w += nwave) {
        const int r = 2 * w + half;
        float ax = 0.0f, ay = 0.0f;
        if (r < n) {
            const int jb = rowptr[r], je = rowptr[r + 1];
            int j = jb;
            for (; j + 7 < je; j += 8) {
                int2 e[8];
#pragma unroll
                for (int u = 0; u < 8; ++u) e[u] = csr[j + u];
                unsigned int g[8];
#pragma unroll
                for (int u = 0; u < 8; ++u)
                    g[u] = sup32[(size_t)e[u].x * 32 + sub];
#pragma unroll
                for (int u = 0; u < 8; ++u) {
                    float v = __int_as_float(e[u].y);
                    ax += v * __uint_as_float(g[u] << 16);
                    ay += v * __uint_as_float(g[u] & 0xffff0000u);
                }
            }
            for (; j + 1 < je; j += 2) {
                int2 e0 = csr[j], e1 = csr[j + 1];
                unsigned int u0 = sup32[(size_t)e0.x * 32 + sub];
                unsigned int u1 = sup32[(size_t)e1.x * 32 + sub];
                float v0 = __int_as_float(e0.y), v1 = __int_as_float(e1.y);
                ax += v0 * __uint_as_float(u0 << 16);
                ay += v0 * __uint_as_float(u0 & 0xffff0000u);
                ax += v1 * __uint_as_float(u1 << 16);
                ay += v1 * __uint_as_float(u1 & 0xffff0000u);
            }
            if (j < je) {
                int2 e = csr[j];
                unsigned int u = sup32[(size_t)e.x * 32 + sub];
                float v = __int_as_float(e.y);
                ax += v * __uint_as_float(u << 16);
                ay += v * __uint_as_float(u & 0xffff0000u);
            }
            float2 o; o.x = ax + b2.x; o.y = ay + b2.y;
            reinterpret_cast<float2*>(out)[(size_t)r * 32 + sub] = o;
        }
    }
}

// ===========================================================================
// Fallback (R1, verified): bias-init + atomic scatter (f32 support)
// ===========================================================================
__global__ __launch_bounds__(256) void init_kernel(const float* __restrict__ bias,
                                                   float* __restrict__ out, int total4) {
    int i = blockIdx.x * 256 + threadIdx.x;
    int stride = gridDim.x * 256;
    for (; i < total4; i += stride) {
        int base4 = (i * 4) & (D - 1);
        float4 bv;
        bv.x = bias[base4 + 0]; bv.y = bias[base4 + 1];
        bv.z = bias[base4 + 2]; bv.w = bias[base4 + 3];
        reinterpret_cast<float4*>(out)[i] = bv;
    }
}

__global__ __launch_bounds__(256) void scatter_kernel(const int* __restrict__ rows,
                                                      const int* __restrict__ cols,
                                                      const float* __restrict__ vals,
                                                      const float* __restrict__ support,
                                                      float* __restrict__ out, int ne) {
    const int wid  = blockIdx.x * 4 + (threadIdx.x >> 6);
    const int lane = threadIdx.x & 63;
    const int nw = gridDim.x * 4;
    for (int e = wid; e < ne; e += nw) {
        const int r = rows[e];
        const int c = cols[e];
        const float v = vals[e];
        unsafeAtomicAdd(&out[(size_t)r * D + lane], v * support[(size_t)c * D + lane]);
    }
}

extern "C" void kernel_launch(void* const* d_in, const int* in_sizes, int n_in,
                              void* d_out, int out_size, void* d_ws, size_t ws_size,
                              hipStream_t stream) {
    const float* x         = (const float*)d_in[0];
    const int*   edge_rows = (const int*)d_in[1];
    const int*   edge_cols = (const int*)d_in[2];
    const float* edge_vals = (const float*)d_in[3];
    const float* w_own     = (const float*)d_in[4];
    const float* w_nbr     = (const float*)d_in[5];
    const float* w_temp    = (const float*)d_in[6];
    const float* bias      = (const float*)d_in[7];

    float* out = (float*)d_out;
    const int n_nodes = in_sizes[0] / D;
    const int n_edges = in_sizes[1];
    const int nb = (n_nodes + RPB - 1) / RPB;

    // ---- workspace layout ----
    char* ws = (char*)d_ws;
    size_t off = 0;
    auto take = [&](size_t bytes) -> char* {
        char* p = ws + off;
        off = (off + bytes + 15) & ~(size_t)15;
        return p;
    };
    __hip_bfloat16* support = (__hip_bfloat16*)take((size_t)n_nodes * D * sizeof(__hip_bfloat16));
    int2* binned = (int2*)take((size_t)n_edges * sizeof(int2));
    int2* csr    = (int2*)take((size_t)n_edges * sizeof(int2));
    int*  rowptr = (int*) take((size_t)(n_nodes + 1) * sizeof(int));
    int*  gcnt   = (int*) take((size_t)nb * CPAD * sizeof(int));
    int*  base   = (int*) take((size_t)(nb + 1) * sizeof(int));
    int*  cursor = (int*) take((size_t)nb * CPAD * sizeof(int));
    const bool full_fits = (off <= ws_size) && (nb <= NBB) && (n_nodes <= (1 << 17));

    if (full_fits) {
        zero_kernel<<<8, 256, 0, stream>>>(gcnt, nb * CPAD);
        bucket_hist_kernel<<<512, 256, 0, stream>>>(edge_rows, n_edges, gcnt, nb);
        bucket_scan_kernel<<<1, 256, 0, stream>>>(gcnt, nb, base, cursor, rowptr, n_nodes);
        fused_scatter_gemm_kernel<<<NSB + NGB, 256, 0, stream>>>(
            edge_rows, edge_cols, edge_vals, n_edges, cursor, nb, binned,
            x, w_own, w_nbr, w_temp, support, n_nodes);
        local_csr_kernel<<<nb * 4, 512, 0, stream>>>(base, binned, rowptr, csr, n_nodes);
        pull2_kernel<<<2048, 256, 0, stream>>>(rowptr, csr, (const unsigned int*)support,
                                               bias, out, n_nodes);
    } else {
        // R1 fallback: f32 support + atomic scatter
        float* support_f = (float*)d_ws;
        gemm_f32_kernel<<<1024, 256, 0, stream>>>(x, w_own, w_nbr, w_temp, support_f, n_nodes);
        int total4 = (n_nodes * D) / 4;
        int blocks = (total4 + 255) / 256; if (blocks > 2048) blocks = 2048;
        init_kernel<<<blocks, 256, 0, stream>>>(bias, out, total4);
        scatter_kernel<<<2048, 256, 0, stream>>>(edge_rows, edge_cols, edge_vals,
                                                 support_f, out, n_edges);
    }
}

// Round 20
// 132.710 us; speedup vs baseline: 1.1058x; 1.1058x over previous
//
#include <hip/hip_runtime.h>
#include <hip/hip_bf16.h>

#define D 64
#define RPB 1024         // rows per bin bucket (rl fits in 10 bits; col 17 bits -> 27)
#define RSH 10           // log2(RPB)
#define NBB 128          // max buckets (n_nodes <= 131072)
#define CPAD 16          // ints per padded counter (64 B line)
#define NSB 512          // scatter-role blocks in the fused kernel (R18-proven optimum)

// ===========================================================================
// Fused bin_scatter + gemm (R18-proven, 51us): blocks [0,NSB) partition edges
// into coarse buckets (latency-bound); blocks [NSB,..) compute
// support = x@(W0+W1+W2) (BW-bound). Data-independent; overlapped on the CUs.
// NSB=512 -> 3125-edge chunks -> ~32-edge (256 B) runs. R19 measured NSB=1024
// worse (68us: halved run length costs more than doubled parallelism gains).
// ===========================================================================
__global__ __launch_bounds__(256) void fused_scatter_gemm_kernel(
        const int* __restrict__ rows, const int* __restrict__ cols,
        const float* __restrict__ vals, int ne,
        int* __restrict__ cursor, int nb, int2* __restrict__ binned,
        const float* __restrict__ x, const float* __restrict__ w0,
        const float* __restrict__ w1, const float* __restrict__ w2,
        __hip_bfloat16* __restrict__ support, int n) {
    __shared__ float Ws[D * D];
    __shared__ float xs[4][D];
    __shared__ int lcnt[NBB];
    __shared__ int lbase[NBB];
    const int tid = threadIdx.x;

    if (blockIdx.x < NSB) {
        // ---- bin_scatter body (R15-proven) ----
        const int ce = (ne + NSB - 1) / NSB;
        const int e0 = blockIdx.x * ce;
        const int e1 = min(ne, e0 + ce);

        for (int i = tid; i < nb; i += 256) lcnt[i] = 0;
        __syncthreads();
        for (int e = e0 + tid; e < e1; e += 256) atomicAdd(&lcnt[rows[e] >> RSH], 1);
        __syncthreads();
        for (int b = tid; b < nb; b += 256) {
            int c = lcnt[b];
            lbase[b] = c ? atomicAdd(&cursor[b * CPAD], c) : 0;
        }
        __syncthreads();
        for (int i = tid; i < nb; i += 256) lcnt[i] = 0;   // reuse as local cursor
        __syncthreads();
        for (int e = e0 + tid; e < e1; e += 256) {
            int r = rows[e];
            int b = r >> RSH;
            int loc = atomicAdd(&lcnt[b], 1);
            int2 cv;
            cv.x = ((r & (RPB - 1)) << 17) | cols[e];
            cv.y = __float_as_int(vals[e]);
            binned[lbase[b] + loc] = cv;
        }
    } else {
        // ---- gemm body (R15-proven) ----
        for (int i = tid; i < D * D; i += 256)
            Ws[i] = w0[i] + w1[i] + w2[i];
        __syncthreads();
        const int wid  = tid >> 6;
        const int lane = tid & 63;
        const int gb = blockIdx.x - NSB;
        int row = gb * 4 + wid;
        const int nw = (gridDim.x - NSB) * 4;
        for (; row < n; row += nw) {
            xs[wid][lane] = x[(size_t)row * D + lane];
            float acc = 0.0f;
#pragma unroll
            for (int k = 0; k < D; ++k) acc += xs[wid][k] * Ws[k * D + lane];
            support[(size_t)row * D + lane] = __float2bfloat16(acc);
        }
    }
}

// f32-support gemm for the fallback path
__global__ __launch_bounds__(256) void gemm_f32_kernel(const float* __restrict__ x,
                                                       const float* __restrict__ w0,
                                                       const float* __restrict__ w1,
                                                       const float* __restrict__ w2,
                                                       float* __restrict__ support,
                                                       int n) {
    __shared__ float Ws[D * D];
    __shared__ float xs[4][D];
    for (int i = threadIdx.x; i < D * D; i += 256)
        Ws[i] = w0[i] + w1[i] + w2[i];
    __syncthreads();
    const int wid  = threadIdx.x >> 6;
    const int lane = threadIdx.x & 63;
    int row = blockIdx.x * 4 + wid;
    const int nw = gridDim.x * 4;
    for (; row < n; row += nw) {
        xs[wid][lane] = x[(size_t)row * D + lane];
        float acc = 0.0f;
#pragma unroll
        for (int k = 0; k < D; ++k) acc += xs[wid][k] * Ws[k * D + lane];
        support[(size_t)row * D + lane] = acc;
    }
}

// ===========================================================================
// zero -> hist (98 coarse buckets) -> scan (R15-proven)
// ===========================================================================
__global__ __launch_bounds__(256) void zero_kernel(int* __restrict__ p, int n) {
    int i = blockIdx.x * 256 + threadIdx.x;
    int stride = gridDim.x * 256;
    for (; i < n; i += stride) p[i] = 0;
}

__global__ __launch_bounds__(256) void bucket_hist_kernel(const int* __restrict__ rows,
                                                          int ne, int* __restrict__ gcnt,
                                                          int nb) {
    __shared__ int lcnt[NBB];
    for (int i = threadIdx.x; i < nb; i += 256) lcnt[i] = 0;
    __syncthreads();
    int i = blockIdx.x * 256 + threadIdx.x;
    int stride = gridDim.x * 256;
    for (; i < ne; i += stride) atomicAdd(&lcnt[rows[i] >> RSH], 1);
    __syncthreads();
    for (int b = threadIdx.x; b < nb; b += 256) {
        int c = lcnt[b];
        if (c) atomicAdd(&gcnt[b * CPAD], c);
    }
}

// 1 block: exclusive scan -> base[nb+1], cursor copy; also rowptr[n] sentinel
__global__ __launch_bounds__(256) void bucket_scan_kernel(const int* __restrict__ gcnt,
                                                          int nb,
                                                          int* __restrict__ base,
                                                          int* __restrict__ cursor,
                                                          int* __restrict__ rowptr,
                                                          int n) {
    __shared__ int ts[256];
    const int tid = threadIdx.x;
    int v = (tid < nb) ? gcnt[tid * CPAD] : 0;
    ts[tid] = v;
    __syncthreads();
    for (int off = 1; off < 256; off <<= 1) {
        int t = (tid >= off) ? ts[tid - off] : 0;
        __syncthreads();
        ts[tid] += t;
        __syncthreads();
    }
    int excl = ts[tid] - v;
    if (tid < nb) { base[tid] = excl; cursor[tid * CPAD] = excl; }
    if (tid == 255) { base[nb] = ts[255]; rowptr[n] = ts[255]; }
}

// ===========================================================================
// local_csr (R14/R15-proven): grid = nb*4 blocks of 512 threads. Block (b,q):
// full 1024-bin hist of bucket b's segment, in-block scan, rowptr for its
// 2 bins/thread, then scatter ONLY quarter q's rows (256) into its
// contiguous window (streaming full-line writes, L2-resident).
// ===========================================================================
__global__ __launch_bounds__(512) void local_csr_kernel(const int* __restrict__ base,
                                                        const int2* __restrict__ binned,
                                                        int* __restrict__ rowptr,
                                                        int2* __restrict__ csr,
                                                        int n) {
    __shared__ int lh[RPB];     // hist -> cursor (4 KB)
    __shared__ int ts[512];
    const int tid = threadIdx.x;
    const int b = blockIdx.x >> 2;
    const int q = blockIdx.x & 3;
    const int jb = base[b], je = base[b + 1];

    lh[2 * tid] = 0; lh[2 * tid + 1] = 0;
    __syncthreads();
    for (int j = jb + tid; j < je; j += 512)
        atomicAdd(&lh[binned[j].x >> 17], 1);
    __syncthreads();

    const int v0 = lh[2 * tid], v1 = lh[2 * tid + 1];
    const int tsum = v0 + v1;
    ts[tid] = tsum;
    __syncthreads();
    for (int off = 1; off < 512; off <<= 1) {
        int t = (tid >= off) ? ts[tid - off] : 0;
        __syncthreads();
        ts[tid] += t;
        __syncthreads();
    }
    int excl = ts[tid] - tsum + jb;
    __syncthreads();           // everyone done reading lh as hist

    const int r0 = b * RPB + 2 * tid;
    lh[2 * tid] = excl;
    if (r0 < n) rowptr[r0] = excl;
    lh[2 * tid + 1] = excl + v0;
    if (r0 + 1 < n) rowptr[r0 + 1] = excl + v0;
    __syncthreads();

    for (int j = jb + tid; j < je; j += 512) {
        int2 e = binned[j];
        int rl = e.x >> 17;
        if ((rl >> 8) == q) {
            int pos = atomicAdd(&lh[rl], 1);
            int2 o; o.x = e.x & 0x1FFFF; o.y = e.y;
            csr[pos] = o;
        }
    }
}

// ===========================================================================
// Pull (R13/R15-proven): 2 rows per wave, uint (2 bf16) gathers, register
// accumulate, 8-deep unroll.
// ===========================================================================
__global__ __launch_bounds__(256) void pull2_kernel(const int* __restrict__ rowptr,
                                                    const int2* __restrict__ csr,
                                                    const unsigned int* __restrict__ sup32,
                                                    const float* __restrict__ bias,
                                                    float* __restrict__ out, int n) {
    const int tid  = threadIdx.x;
    const int lane = tid & 63;
    const int half = lane >> 5;
    const int sub  = lane & 31;
    const int wave = blockIdx.x * 4 + (tid >> 6);
    const int nwave = gridDim.x * 4;
    const float2 b2 = reinterpret_cast<const float2*>(bias)[sub];

    for (int w = wave; 2 * w < n; w += nwave) {
        const int r = 2 * w + half;
        float ax = 0.0f, ay = 0.0f;
        if (r < n) {
            const int jb = rowptr[r], je = rowptr[r + 1];
            int j = jb;
            for (; j + 7 < je; j += 8) {
                int2 e[8];
#pragma unroll
                for (int u = 0; u < 8; ++u) e[u] = csr[j + u];
                unsigned int g[8];
#pragma unroll
                for (int u = 0; u < 8; ++u)
                    g[u] = sup32[(size_t)e[u].x * 32 + sub];
#pragma unroll
                for (int u = 0; u < 8; ++u) {
                    float v = __int_as_float(e[u].y);
                    ax += v * __uint_as_float(g[u] << 16);
                    ay += v * __uint_as_float(g[u] & 0xffff0000u);
                }
            }
            for (; j + 1 < je; j += 2) {
                int2 e0 = csr[j], e1 = csr[j + 1];
                unsigned int u0 = sup32[(size_t)e0.x * 32 + sub];
                unsigned int u1 = sup32[(size_t)e1.x * 32 + sub];
                float v0 = __int_as_float(e0.y), v1 = __int_as_float(e1.y);
                ax += v0 * __uint_as_float(u0 << 16);
                ay += v0 * __uint_as_float(u0 & 0xffff0000u);
                ax += v1 * __uint_as_float(u1 << 16);
                ay += v1 * __uint_as_float(u1 & 0xffff0000u);
            }
            if (j < je) {
                int2 e = csr[j];
                unsigned int u = sup32[(size_t)e.x * 32 + sub];
                float v = __int_as_float(e.y);
                ax += v * __uint_as_float(u << 16);
                ay += v * __uint_as_float(u & 0xffff0000u);
            }
            float2 o; o.x = ax + b2.x; o.y = ay + b2.y;
            reinterpret_cast<float2*>(out)[(size_t)r * 32 + sub] = o;
        }
    }
}

// ===========================================================================
// Fallback (R1, verified): bias-init + atomic scatter (f32 support)
// ===========================================================================
__global__ __launch_bounds__(256) void init_kernel(const float* __restrict__ bias,
                                                   float* __restrict__ out, int total4) {
    int i = blockIdx.x * 256 + threadIdx.x;
    int stride = gridDim.x * 256;
    for (; i < total4; i += stride) {
        int base4 = (i * 4) & (D - 1);
        float4 bv;
        bv.x = bias[base4 + 0]; bv.y = bias[base4 + 1];
        bv.z = bias[base4 + 2]; bv.w = bias[base4 + 3];
        reinterpret_cast<float4*>(out)[i] = bv;
    }
}

__global__ __launch_bounds__(256) void scatter_kernel(const int* __restrict__ rows,
                                                      const int* __restrict__ cols,
                                                      const float* __restrict__ vals,
                                                      const float* __restrict__ support,
                                                      float* __restrict__ out, int ne) {
    const int wid  = blockIdx.x * 4 + (threadIdx.x >> 6);
    const int lane = threadIdx.x & 63;
    const int nw = gridDim.x * 4;
    for (int e = wid; e < ne; e += nw) {
        const int r = rows[e];
        const int c = cols[e];
        const float v = vals[e];
        unsafeAtomicAdd(&out[(size_t)r * D + lane], v * support[(size_t)c * D + lane]);
    }
}

extern "C" void kernel_launch(void* const* d_in, const int* in_sizes, int n_in,
                              void* d_out, int out_size, void* d_ws, size_t ws_size,
                              hipStream_t stream) {
    const float* x         = (const float*)d_in[0];
    const int*   edge_rows = (const int*)d_in[1];
    const int*   edge_cols = (const int*)d_in[2];
    const float* edge_vals = (const float*)d_in[3];
    const float* w_own     = (const float*)d_in[4];
    const float* w_nbr     = (const float*)d_in[5];
    const float* w_temp    = (const float*)d_in[6];
    const float* bias      = (const float*)d_in[7];

    float* out = (float*)d_out;
    const int n_nodes = in_sizes[0] / D;
    const int n_edges = in_sizes[1];
    const int nb = (n_nodes + RPB - 1) / RPB;

    // ---- workspace layout ----
    char* ws = (char*)d_ws;
    size_t off = 0;
    auto take = [&](size_t bytes) -> char* {
        char* p = ws + off;
        off = (off + bytes + 15) & ~(size_t)15;
        return p;
    };
    __hip_bfloat16* support = (__hip_bfloat16*)take((size_t)n_nodes * D * sizeof(__hip_bfloat16));
    int2* binned = (int2*)take((size_t)n_edges * sizeof(int2));
    int2* csr    = (int2*)take((size_t)n_edges * sizeof(int2));
    int*  rowptr = (int*) take((size_t)(n_nodes + 1) * sizeof(int));
    int*  gcnt   = (int*) take((size_t)nb * CPAD * sizeof(int));
    int*  base   = (int*) take((size_t)(nb + 1) * sizeof(int));
    int*  cursor = (int*) take((size_t)nb * CPAD * sizeof(int));
    const bool full_fits = (off <= ws_size) && (nb <= NBB) && (n_nodes <= (1 << 17));

    if (full_fits) {
        zero_kernel<<<8, 256, 0, stream>>>(gcnt, nb * CPAD);
        bucket_hist_kernel<<<512, 256, 0, stream>>>(edge_rows, n_edges, gcnt, nb);
        bucket_scan_kernel<<<1, 256, 0, stream>>>(gcnt, nb, base, cursor, rowptr, n_nodes);
        fused_scatter_gemm_kernel<<<NSB + 2048, 256, 0, stream>>>(
            edge_rows, edge_cols, edge_vals, n_edges, cursor, nb, binned,
            x, w_own, w_nbr, w_temp, support, n_nodes);
        local_csr_kernel<<<nb * 4, 512, 0, stream>>>(base, binned, rowptr, csr, n_nodes);
        pull2_kernel<<<2048, 256, 0, stream>>>(rowptr, csr, (const unsigned int*)support,
                                               bias, out, n_nodes);
    } else {
        // R1 fallback: f32 support + atomic scatter
        float* support_f = (float*)d_ws;
        gemm_f32_kernel<<<1024, 256, 0, stream>>>(x, w_own, w_nbr, w_temp, support_f, n_nodes);
        int total4 = (n_nodes * D) / 4;
        int blocks = (total4 + 255) / 256; if (blocks > 2048) blocks = 2048;
        init_kernel<<<blocks, 256, 0, stream>>>(bias, out, total4);
        scatter_kernel<<<2048, 256, 0, stream>>>(edge_rows, edge_cols, edge_vals,
                                                 support_f, out, n_edges);
    }
}